// Round 4
// baseline (164.456 us; speedup 1.0000x reference)
//
#include <hip/hip_runtime.h>
#include <math.h>

#define M_SPATIAL 2097152  // 128^3

typedef float f32x2 __attribute__((ext_vector_type(2)));

__device__ __forceinline__ float wave_redf(float v) {
#pragma unroll
  for (int o = 32; o > 0; o >>= 1) v += __shfl_down(v, o, 64);
  return v;
}
__device__ __forceinline__ double wave_redd(double v) {
#pragma unroll
  for (int o = 32; o > 0; o >>= 1) v += __shfl_down(v, o, 64);
  return v;
}
// Forced 3-input min (VOP3 v_min3_f32); exact, order-independent.
__device__ __forceinline__ float min3f(float a, float b, float c) {
  float d;
  asm("v_min3_f32 %0, %1, %2, %3" : "=v"(d) : "v"(a), "v"(b), "v"(c));
  return d;
}

// part layout (doubles):
// [0..1023]=ce  [1024..2047]=p  [2048..3071]=pt  [3072..4095]=t
// [4096..4351]=dist (256 kCD blocks)

// ---------------------------------------------------------------------------
// kAB: X-axis EDT (blocked parallel scan) FUSED with CE + dice partials.
// xc is already batch-offset -> spatial-only index sp (round-2 OOB lesson).
// Writes h = gX + y^2 for the Y pass.
// ---------------------------------------------------------------------------
__global__ __launch_bounds__(256) void kAB(const int* __restrict__ y,
                                           const float* __restrict__ outputs,
                                           float* __restrict__ g,
                                           double* __restrict__ part) {
  int blk = blockIdx.x;            // b*512 + yy*4 + zq
  int b  = blk >> 9;
  int yy = (blk >> 2) & 127;
  int zq = blk & 3;
  int t  = threadIdx.x;
  int c  = t >> 5;                 // x-chunk 0..7 (16 x each)
  int zl = t & 31;                 // z within 32-chunk
  int x0 = c * 16;
  size_t sp   = (size_t)yy * 128 + (size_t)zq * 32 + zl;    // spatial-only
  size_t base = (size_t)b * M_SPATIAL + sp;                 // batch + spatial
  const float* xc = outputs + (size_t)(b * 2 + 1) * M_SPATIAL;

  int yb[16];
  float xv[16];
#pragma unroll
  for (int k = 0; k < 16; ++k) yb[k] = y[base + (size_t)(x0 + k) * 16384];
#pragma unroll
  for (int k = 0; k < 16; ++k) xv[k] = xc[sp + (size_t)(x0 + k) * 16384];

  int lastE = -200, nextE = 400;
#pragma unroll
  for (int k = 0; k < 16; ++k) lastE = (yb[k] == 1) ? lastE : (x0 + k);
#pragma unroll
  for (int k = 15; k >= 0; --k) nextE = (yb[k] == 1) ? nextE : (x0 + k);

  __shared__ int lE[8][32];
  __shared__ int nE[8][32];
  lE[c][zl] = lastE;
  nE[c][zl] = nextE;
  __syncthreads();

  int carryL = -200, carryN = 400;
#pragma unroll
  for (int q = 0; q < 7; ++q) {
    if (q < c)     carryL = max(carryL, lE[q][zl]);
    if (q + 1 > c) carryN = min(carryN, nE[q + 1][zl]);
  }

  float yy2f = (float)(yy * yy);
  float hinf = 1000000.f + yy2f;

  int df[16];
  int ll = carryL;
#pragma unroll
  for (int k = 0; k < 16; ++k) {
    ll = (yb[k] == 1) ? ll : (x0 + k);
    df[k] = min(x0 + k - ll, 200);
  }
  float ov[16];
  int nn = carryN;
#pragma unroll
  for (int k = 15; k >= 0; --k) {
    nn = (yb[k] == 1) ? nn : (x0 + k);
    int m = min(df[k], min(nn - (x0 + k), 200));
    ov[k] = (m >= 128) ? hinf : ((float)(m * m) + yy2f);
  }
#pragma unroll
  for (int k = 0; k < 16; ++k) g[base + (size_t)(x0 + k) * 16384] = ov[k];

  float ce = 0.f, ps = 0.f, pts = 0.f, tsum = 0.f;
#pragma unroll
  for (int k = 0; k < 16; ++k) {
    float tt = (yb[k] == 1) ? 1.0f : 0.0f;
    float xx = xv[k];
    ce += fmaxf(xx, 0.0f) - xx * tt + log1pf(expf(-fabsf(xx)));
    float p = 1.0f / (1.0f + expf(-xx));
    ps += p; pts += p * tt; tsum += tt;
  }
  float r0 = wave_redf(ce), r1 = wave_redf(ps), r2 = wave_redf(pts), r3 = wave_redf(tsum);
  __shared__ float sm[4][4];
  int lane = t & 63, w = t >> 6;
  if (lane == 0) { sm[w][0] = r0; sm[w][1] = r1; sm[w][2] = r2; sm[w][3] = r3; }
  __syncthreads();
  if (t == 0) {
    part[blk]        = (double)(sm[0][0] + sm[1][0] + sm[2][0] + sm[3][0]);
    part[1024 + blk] = (double)(sm[0][1] + sm[1][1] + sm[2][1] + sm[3][1]);
    part[2048 + blk] = (double)(sm[0][2] + sm[1][2] + sm[2][2] + sm[3][2]);
    part[3072 + blk] = (double)(sm[0][3] + sm[1][3] + sm[2][3] + sm[3][3]);
  }
}

// ---------------------------------------------------------------------------
// kCD: Y pass + Z pass + dist loss, one block per (b,x) slab.
// Round-3 counters: VALU-issue-bound (VALUBusy 91%, HBM 4.6%, conflicts 0,
// Occupancy 19%). This version:
//   * 1024 threads (16 waves -> 4 waves/SIMD, 2x the latency hiding),
//     NK=16 outputs/thread (same total VALU work).
//   * inner step = 1 v_pk_fma_f32 (f32x2) + 1 forced v_min3_f32 per
//     (2 parabolas x output): 2 VALU vs previous 3-4.
//   * f32x2 counter jv += {2,2} replaces per-iter int->float converts.
// All envelope values are exact integers < 2^21 in fp32 -> bit-exact EDT.
// ---------------------------------------------------------------------------
__global__ __launch_bounds__(1024) void kCD(const float* __restrict__ g,
                                            const float* __restrict__ od,
                                            double* __restrict__ part) {
  __shared__ float sbuf[128 * 132];   // 67.6 KB, reused across passes
  __shared__ float sred[16];
  int blk = blockIdx.x;               // b*128 + x
  int b = blk >> 7, xx = blk & 127;
  int t = threadIdx.x;
  size_t rb = (size_t)b * M_SPATIAL + (size_t)xx * 16384;

  // od prefetch (Z-pass operand) issued first: 16 floats, lands during Y pass.
  int yl = t >> 3, izb = (t & 7) * 16;
  size_t odb = (size_t)(2 * b + 1) * M_SPATIAL + (size_t)xx * 16384 +
               (size_t)yl * 128 + (size_t)izb;
  const float4* o4 = (const float4*)(od + odb);
  float4 ovv[4];
#pragma unroll
  for (int r = 0; r < 4; ++r) ovv[r] = o4[r];

  // Stage the slab: 4096 float4, coalesced (bank pattern 2-way max = free).
  const float4* g4 = (const float4*)(g + rb);
#pragma unroll
  for (int r = 0; r < 4; ++r) {
    int i4 = t + r * 1024;            // 0..4095
    float4 v = g4[i4];
    int flat = i4 * 4;
    int ys = flat >> 7, zs = flat & 127;
    *(float4*)&sbuf[ys * 132 + zs] = v;
  }
  __syncthreads();

  // ---- Y pass: z = t&127 fixed, 16 i's.
  {
    int z = t & 127, ibase = (t >> 7) * 16;
    float zq = (float)(z * z);
    float best[16];
    f32x2 mc2[16];
#pragma unroll
    for (int k = 0; k < 16; ++k) {
      best[k] = 3.0e38f;
      float m = -2.0f * (float)(ibase + k);
      mc2[k] = (f32x2){m, m};
    }
    f32x2 jv = {0.0f, 1.0f};
#pragma unroll 4
    for (int j = 0; j < 128; j += 2) {
      f32x2 hv = {sbuf[j * 132 + z], sbuf[(j + 1) * 132 + z]};
#pragma unroll
      for (int k = 0; k < 16; ++k) {
        f32x2 v = __builtin_elementwise_fma(mc2[k], jv, hv);
        best[k] = min3f(v.x, v.y, best[k]);
      }
      jv += (f32x2){2.0f, 2.0f};
    }
    __syncthreads();                  // everyone done READING sbuf
#pragma unroll
    for (int k = 0; k < 16; ++k) {
      int i = ibase + k;
      float dY = (float)(i * i) + best[k];   // exact int
      sbuf[z * 129 + i] = dY + zq;           // h for Z pass, transposed layout
    }
  }
  __syncthreads();

  // ---- Z pass + dist loss: y = t>>3 fixed, 16 i(z)'s.
  {
    float best[16];
    f32x2 mc2[16];
#pragma unroll
    for (int k = 0; k < 16; ++k) {
      best[k] = 3.0e38f;
      float m = -2.0f * (float)(izb + k);
      mc2[k] = (f32x2){m, m};
    }
    f32x2 jv = {0.0f, 1.0f};
#pragma unroll 4
    for (int j = 0; j < 128; j += 2) {
      f32x2 hv = {sbuf[j * 129 + yl], sbuf[(j + 1) * 129 + yl]};
#pragma unroll
      for (int k = 0; k < 16; ++k) {
        f32x2 v = __builtin_elementwise_fma(mc2[k], jv, hv);
        best[k] = min3f(v.x, v.y, best[k]);
      }
      jv += (f32x2){2.0f, 2.0f};
    }
    const float* of = (const float*)ovv;
    float dist = 0.f;
#pragma unroll
    for (int k = 0; k < 16; ++k) {
      int i = izb + k;
      float dv = (float)(i * i) + best[k];   // exact squared EDT
      if (dv > 0.f) dist += fabsf(of[k] - sqrtf(dv));
    }
    float r = wave_redf(dist);
    int lane = t & 63, w = t >> 6;
    if (lane == 0) sred[w] = r;
  }
  __syncthreads();
  if (t == 0) {
    float s = 0.f;
#pragma unroll
    for (int q = 0; q < 16; ++q) s += sred[q];
    part[4096 + blk] = (double)s;
  }
}

// ---------------------------------------------------------------------------
// k_final: reduce partials (1024 ce/dice slots, 256 dist slots) -> loss.
// ---------------------------------------------------------------------------
__global__ __launch_bounds__(256) void k_final(const double* __restrict__ part,
                                               const float* __restrict__ wptr,
                                               float* __restrict__ out) {
  int i = threadIdx.x;
  double ce  = part[i] + part[i + 256] + part[i + 512] + part[i + 768];
  double p0  = part[1024 + i] + part[1024 + i + 256];
  double p1  = part[1536 + i] + part[1536 + i + 256];
  double pt0 = part[2048 + i] + part[2048 + i + 256];
  double pt1 = part[2560 + i] + part[2560 + i + 256];
  double t0  = part[3072 + i] + part[3072 + i + 256];
  double t1  = part[3584 + i] + part[3584 + i + 256];
  double ds  = part[4096 + i];   // 256 kCD blocks, one slot per thread

  ce = wave_redd(ce); p0 = wave_redd(p0); p1 = wave_redd(p1);
  pt0 = wave_redd(pt0); pt1 = wave_redd(pt1);
  t0 = wave_redd(t0); t1 = wave_redd(t1); ds = wave_redd(ds);

  __shared__ double sm[4][8];
  int lane = threadIdx.x & 63, w = threadIdx.x >> 6;
  if (lane == 0) {
    sm[w][0] = ce; sm[w][1] = p0; sm[w][2] = p1; sm[w][3] = pt0;
    sm[w][4] = pt1; sm[w][5] = t0; sm[w][6] = t1; sm[w][7] = ds;
  }
  __syncthreads();
  if (threadIdx.x == 0) {
    double a[8];
    for (int q = 0; q < 8; ++q) a[q] = sm[0][q] + sm[1][q] + sm[2][q] + sm[3][q];
    double cem = a[0] / 4194304.0;
    double dice0 = (2.0 * a[3] + 1.0) / (a[1] + a[5] + 1.0);
    double dice1 = (2.0 * a[4] + 1.0) / (a[2] + a[6] + 1.0);
    double ldice = 1.0 - 0.5 * (dice0 + dice1);
    double msum = a[5] + a[6];
    double ldist = (msum == 0.0) ? 0.0 : a[7] / fmax(msum, 1e-12);
    out[0] = (float)(cem + ldice + (double)wptr[0] * ldist);
  }
}

extern "C" void kernel_launch(void* const* d_in, const int* in_sizes, int n_in,
                              void* d_out, int out_size, void* d_ws, size_t ws_size,
                              hipStream_t stream) {
  const float* outputs      = (const float*)d_in[0];
  const float* outputs_dist = (const float*)d_in[1];
  const int*   y            = (const int*)d_in[2];
  const float* wptr         = (const float*)d_in[3];
  float* out = (float*)d_out;

  double* part = (double*)d_ws;                    // 4352 doubles
  float* g = (float*)((char*)d_ws + 65536);        // 16 MiB h field

  kAB<<<1024, 256, 0, stream>>>(y, outputs, g, part);      // X scan + CE/dice
  kCD<<<256, 1024, 0, stream>>>(g, outputs_dist, part);    // Y+Z EDT + dist
  k_final<<<1, 256, 0, stream>>>(part, wptr, out);
}